// Round 6
// baseline (313.831 us; speedup 1.0000x reference)
//
#include <hip/hip_runtime.h>
#include <hip/hip_bf16.h>

// Problem constants (B=1)
#define T_SEQ 2048
#define D_MODEL 2048
#define NH 16
#define HDIM 128
#define RD_ROT 64

typedef __bf16 bf16x8 __attribute__((ext_vector_type(8)));
typedef float f32x4 __attribute__((ext_vector_type(4)));
typedef float f32x16 __attribute__((ext_vector_type(16)));

__device__ __forceinline__ void async_copy16(const __bf16* g, __bf16* l) {
    __builtin_amdgcn_global_load_lds(
        (const __attribute__((address_space(1))) void*)g,
        (__attribute__((address_space(3))) void*)l, 16, 0, 0);
}

// ---------------------------------------------------------------------------
// Cast fp32 -> bf16 for the 5 GEMM operands (hidden, Wq, Wk, Wv, Wo).
// ---------------------------------------------------------------------------
__global__ __launch_bounds__(256) void cast_kernel(
    const float* __restrict__ s0, const float* __restrict__ s1, const float* __restrict__ s2,
    const float* __restrict__ s3, const float* __restrict__ s4,
    __bf16* __restrict__ d0, __bf16* __restrict__ d1, __bf16* __restrict__ d2,
    __bf16* __restrict__ d3, __bf16* __restrict__ d4)
{
    const float* s; __bf16* d;
    switch (blockIdx.y) {
        case 0: s = s0; d = d0; break;
        case 1: s = s1; d = d1; break;
        case 2: s = s2; d = d2; break;
        case 3: s = s3; d = d3; break;
        default: s = s4; d = d4; break;
    }
    size_t base = (size_t)blockIdx.x * D_MODEL + (size_t)threadIdx.x * 8;
    f32x4 a = *(const f32x4*)(s + base);
    f32x4 b = *(const f32x4*)(s + base + 4);
    bf16x8 o;
    #pragma unroll
    for (int i = 0; i < 4; i++) { o[i] = (__bf16)a[i]; o[i + 4] = (__bf16)b[i]; }
    *(bf16x8*)(d + base) = o;
}

// ---------------------------------------------------------------------------
// LDS fragment reads. Rows are 64 bf16 = 128 B = exactly 32 banks; st_16x32
// XOR swizzle (16B-chunk ^= row&7), realized on the write side by
// pre-swizzling the GLOBAL source of global_load_lds (dest stays linear).
// 16x16x32 frag: lane l -> row (l&15), chunk ((s*4 + (l>>4)) ^ (row&7)).
// 32x32x16 frag: lane l -> row (l&31), chunk ((s*2 + (l>>5)) ^ (row&7))
//   (A/B k = (l>>5)*8 + j within kstep s; ISA sec 10 layout).
// ---------------------------------------------------------------------------
__device__ __forceinline__ bf16x8 ld_frag(const __bf16* lds, int rr, int s, int quad, int r7) {
    return *(const bf16x8*)&lds[rr * 64 + ((((s << 2) + quad) ^ r7) << 3)];
}
__device__ __forceinline__ bf16x8 ld_frag32(const __bf16* lds, int rr, int s, int hi) {
    return *(const bf16x8*)&lds[rr * 64 + ((((s << 1) + hi) ^ (rr & 7)) << 3)];
}

// ---------------------------------------------------------------------------
// FUSED QKV GEMM: C = A @ Bf^T, Bf = [Wq;Wk;Wv] (6144x2048). BM=256, BN=192,
// BK=64 -> grid 8 x 32 = 256 blocks = 1/CU. 512 threads, 8 waves in a
// 4M x 2N grid: per-wave 64 x 96 via 32x32x16 MFMA (2 Mfrag x 3 Nfrag).
// R6: 32x32 frags double arithmetic intensity per LDS byte vs 16x16 at equal
// span and run at 2495 vs 2075 TF; 4Mx2N cuts per-wave LDS traffic
// (Mspan+Nspan 176->160). Per-CU per-K-tile: LDS-read 1880cy, MFMA 1550cy,
// staging ~1000cy (was 2070/1862/1000 serialized = 4330).
// Schedule (R5-verified region structure, reads feed NEXT phase):
//   ph1(t): read a1(t)[4]; stage B(t+2)[3] | 12 MFMA32 mf0 (a0,bv)
//           | vmcnt(3) | bar
//   ph2(t): stage A(t+2)[4] | 12 MFMA32 mf1 (a1,bv)
//           | read bv(t+1)[12] + a0(t+1)[4] (WAR on bv/a0: in-order issue,
//             MFMA operands captured at issue; sched_barrier keeps order) | bar
// Ledger: at ph1(t) vmcnt point outstanding = A(t+1)[4] + B(t+2)[3] ->
// vmcnt(3) drains A(t+1), keeps B(t+2). Tails: pf? 3 : 0.
// Region safety: B-region(buf b) last ds_read at ph2(t-1)-end, retires
// ~200cy into ph1(t); B(t+2) stage writes land >=500cy after ph1 start -> ok.
// A-region read a1 at ph1(t)-start; A(t+2) staged ph2(t) after barrier -> ok.
// ---------------------------------------------------------------------------
__global__ __launch_bounds__(512, 2) void gemm_qkv_fused_kernel(
    const __bf16* __restrict__ A,      // 2048 x 2048
    const __bf16* __restrict__ Bf,     // 6144 x 2048 (Wq;Wk;Wv)
    __bf16* __restrict__ Cf)           // 3 x (2048 x 2048) contiguous
{
    constexpr int BM = 256, BN = 192, BK = 64, KD = D_MODEL, NT = KD / BK;  // 32

    __shared__ __align__(16) __bf16 As[2][BM * BK];   // 2 x 32 KB
    __shared__ __align__(16) __bf16 Bs[2][BN * BK];   // 2 x 24 KB   (112 KB total)

    const int bm = (int)blockIdx.x * BM;      // mtile 0..7  (== XCD)
    const int bn = (int)blockIdx.y * BN;      // ntile 0..31

    const int tid  = threadIdx.x;
    const int lane = tid & 63;
    const int wave = tid >> 6;      // 0..7
    const int l31  = lane & 31;
    const int hi   = lane >> 5;     // 0..1
    const int wm   = wave >> 1;     // 0..3 : 64-row M slice
    const int wn   = wave & 1;      // 0..1 : 96-col N slice

    // Staging (unchanged from R5): one async_copy16 = 512 thr x 16 B = 64 rows.
    const int sr8 = lane >> 3;                 // 0..7
    const int sck = (lane & 7) ^ sr8;
    const __bf16* Ap = A  + (size_t)(bm + wave * 8 + sr8) * KD + sck * 8;
    const __bf16* Bp = Bf + (size_t)(bn + wave * 8 + sr8) * KD + sck * 8;

    auto stageA = [&](int buf, int kt) {       // 4 issues: 256 rows
        #pragma unroll
        for (int j = 0; j < 4; j++)
            async_copy16(Ap + (size_t)(j * 64) * KD + kt, &As[buf][j * 4096 + wave * 512]);
    };
    auto stageB = [&](int buf, int kt) {       // 3 issues: 192 rows
        #pragma unroll
        for (int j = 0; j < 3; j++)
            async_copy16(Bp + (size_t)(j * 64) * KD + kt, &Bs[buf][j * 4096 + wave * 512]);
    };

    f32x16 acc[2][3] = {};        // 96 VGPR
    bf16x8 a0[4], a1[4];          // mf0 / mf1, ksteps 0..3 (32 VGPR)
    bf16x8 bv[3][4];              // nf x kstep (48 VGPR), single-banked

    // ---- prologue: stage t0 -> buf0, t1 -> buf1; first operands ----
    stageB(0, 0);  stageA(0, 0);
    stageB(1, BK); stageA(1, BK);
    asm volatile("s_waitcnt vmcnt(7)" ::: "memory");   // t0 landed (7 ops), t1 in flight
    __builtin_amdgcn_s_barrier();
    __builtin_amdgcn_sched_barrier(0);
    #pragma unroll
    for (int nf = 0; nf < 3; nf++)
        #pragma unroll
        for (int s = 0; s < 4; s++)
            bv[nf][s] = ld_frag32(Bs[0], wn * 96 + nf * 32 + l31, s, hi);
    #pragma unroll
    for (int s = 0; s < 4; s++)
        a0[s] = ld_frag32(As[0], wm * 64 + l31, s, hi);

    for (int t = 0; t < NT; t++) {
        const int b = t & 1;
        const __bf16* Asb = As[b];
        const __bf16* Aso = As[b ^ 1];
        const __bf16* Bso = Bs[b ^ 1];
        const bool pf = (t + 2 < NT);
        const bool rd = (t + 1 < NT);
        const int ktp = (t + 2) * BK;

        // ---- ph1: read a1(t); stage B(t+2); MFMA mf0; drain; bar ----
        #pragma unroll
        for (int s = 0; s < 4; s++)
            a1[s] = ld_frag32(Asb, wm * 64 + 32 + l31, s, hi);
        if (pf) stageB(b, ktp);
        __builtin_amdgcn_sched_barrier(0);
        __builtin_amdgcn_s_setprio(1);
        #pragma unroll
        for (int s = 0; s < 4; s++)
            #pragma unroll
            for (int nf = 0; nf < 3; nf++)
                acc[0][nf] = __builtin_amdgcn_mfma_f32_32x32x16_bf16(a0[s], bv[nf][s], acc[0][nf], 0, 0, 0);
        __builtin_amdgcn_s_setprio(0);
        __builtin_amdgcn_sched_barrier(0);
        if (pf) asm volatile("s_waitcnt vmcnt(3)" ::: "memory");   // drain t+1, keep B(t+2)
        else    asm volatile("s_waitcnt vmcnt(0)" ::: "memory");   // tail
        __builtin_amdgcn_s_barrier();
        __builtin_amdgcn_sched_barrier(0);

        // ---- ph2: stage A(t+2); MFMA mf1; read bv,a0 of t+1; bar ----
        if (pf) stageA(b, ktp);
        __builtin_amdgcn_sched_barrier(0);
        __builtin_amdgcn_s_setprio(1);
        #pragma unroll
        for (int s = 0; s < 4; s++)
            #pragma unroll
            for (int nf = 0; nf < 3; nf++)
                acc[1][nf] = __builtin_amdgcn_mfma_f32_32x32x16_bf16(a1[s], bv[nf][s], acc[1][nf], 0, 0, 0);
        __builtin_amdgcn_s_setprio(0);
        __builtin_amdgcn_sched_barrier(0);
        if (rd) {
            #pragma unroll
            for (int nf = 0; nf < 3; nf++)
                #pragma unroll
                for (int s = 0; s < 4; s++)
                    bv[nf][s] = ld_frag32(Bso, wn * 96 + nf * 32 + l31, s, hi);
            #pragma unroll
            for (int s = 0; s < 4; s++)
                a0[s] = ld_frag32(Aso, wm * 64 + l31, s, hi);
        }
        __builtin_amdgcn_sched_barrier(0);
        __builtin_amdgcn_s_barrier();
        __builtin_amdgcn_sched_barrier(0);
    }

    // ---- epilogue: 32x32 C/D layout (col=lane&31, row=(r&3)+8*(r>>2)+4*hi),
    //      split fused N back into q/k/v matrices ----
    #pragma unroll
    for (int nf = 0; nf < 3; nf++) {
        const int col0 = bn + wn * 96 + nf * 32;          // mult of 32
        const int mat  = col0 >> 11;                      // 0..2
        const int colr = (col0 & 2047) + l31;
        __bf16* Cm = Cf + (size_t)mat * T_SEQ * D_MODEL;
        #pragma unroll
        for (int mf = 0; mf < 2; mf++) {
            #pragma unroll
            for (int r = 0; r < 16; r++) {
                const size_t row = (size_t)(bm + wm * 64 + mf * 32 + (r & 3) + 8 * (r >> 2) + 4 * hi);
                Cm[row * D_MODEL + colr] = (__bf16)acc[mf][nf][r];
            }
        }
    }
}

// ---------------------------------------------------------------------------
// Projection GEMM: out = attn @ Wo^T, fp32 direct stores. 128x128 tile, BK=64,
// 256 threads (4 waves, 2x2), grid 16x16 = 256 blocks (full CU fill, XCD
// swizzle). v3 pipelined 4-phase schedule, reads 4/4/4/4 per phase.
// ---------------------------------------------------------------------------
__global__ __launch_bounds__(256) void proj_gemm_kernel(
    const __bf16* __restrict__ A, const __bf16* __restrict__ Bmat, float* __restrict__ C)
{
    constexpr int BM = 128, BK = 64, KD = D_MODEL, NT = KD / BK;   // 32 K-tiles

    __shared__ __align__(16) __bf16 As[2][BM * BK];   // 2 x 16 KB
    __shared__ __align__(16) __bf16 Bs[2][BM * BK];   // 2 x 16 KB

    // XCD swizzle over 256 blocks (256 % 8 == 0 -> bijective)
    const int flat = (int)blockIdx.x + 16 * (int)blockIdx.y;
    const int swz  = (flat & 7) * 32 + (flat >> 3);
    const int bm   = (swz & 15) * BM;
    const int bn   = (swz >> 4) * BM;

    const int tid  = threadIdx.x;
    const int lane = tid & 63;
    const int wave = tid >> 6;      // 0..3
    const int r15  = lane & 15;
    const int quad = lane >> 4;
    const int r7   = r15 & 7;
    const int wm   = (wave >> 1) * 64;
    const int wn   = (wave & 1) * 64;

    const int sr8 = lane >> 3;
    const int sck = (lane & 7) ^ sr8;
    const __bf16* Ap = A    + (size_t)(bm + wave * 8 + sr8) * KD + sck * 8;
    const __bf16* Bp = Bmat + (size_t)(bn + wave * 8 + sr8) * KD + sck * 8;

    auto stageA = [&](int buf, int kt) {
        #pragma unroll
        for (int j = 0; j < 4; j++)
            async_copy16(Ap + (size_t)(j * 32) * KD + kt, &As[buf][wave * 512 + j * 2048]);
    };
    auto stageB = [&](int buf, int kt) {
        #pragma unroll
        for (int j = 0; j < 4; j++)
            async_copy16(Bp + (size_t)(j * 32) * KD + kt, &Bs[buf][wave * 512 + j * 2048]);
    };

    f32x4 acc[4][4] = {};
    bf16x8 a0[2][2], a1[2][2], b0[2][2], b1[2][2];

    auto mfma8 = [&](int mb, int nb, bf16x8 (&av)[2][2], bf16x8 (&bv)[2][2]) {
        #pragma unroll
        for (int mf = 0; mf < 2; mf++)
            #pragma unroll
            for (int nf = 0; nf < 2; nf++)
                #pragma unroll
                for (int s = 0; s < 2; s++)
                    acc[mb + mf][nb + nf] =
                        __builtin_amdgcn_mfma_f32_16x16x32_bf16(av[mf][s], bv[nf][s], acc[mb + mf][nb + nf], 0, 0, 0);
    };

    // prologue: t0 -> buf0, t1 -> buf1
    stageB(0, 0);  stageA(0, 0);
    stageB(1, BK); stageA(1, BK);
    asm volatile("s_waitcnt vmcnt(8)" ::: "memory");
    __builtin_amdgcn_s_barrier();
    __builtin_amdgcn_sched_barrier(0);
    #pragma unroll
    for (int mf = 0; mf < 2; mf++)
        #pragma unroll
        for (int s = 0; s < 2; s++)
            a0[mf][s] = ld_frag(As[0], wm + mf * 16 + r15, s, quad, r7);
    #pragma unroll
    for (int nf = 0; nf < 2; nf++)
        #pragma unroll
        for (int s = 0; s < 2; s++)
            b0[nf][s] = ld_frag(Bs[0], wn + nf * 16 + r15, s, quad, r7);

    for (int t = 0; t < NT; t++) {
        const int b = t & 1;
        const __bf16* Asb = As[b];
        const __bf16* Bsb = Bs[b];
        const __bf16* Aso = As[b ^ 1];
        const __bf16* Bso = Bs[b ^ 1];
        const bool pf = (t + 2 < NT);
        const bool rd = (t + 1 < NT);
        const int ktp = (t + 2) * BK;

        // ph1: read b1(t); MFMA q1
        #pragma unroll
        for (int nf = 0; nf < 2; nf++)
            #pragma unroll
            for (int s = 0; s < 2; s++)
                b1[nf][s] = ld_frag(Bsb, wn + 32 + nf * 16 + r15, s, quad, r7);
        __builtin_amdgcn_sched_barrier(0);
        __builtin_amdgcn_s_setprio(1);
        mfma8(0, 0, a0, b0);
        __builtin_amdgcn_s_setprio(0);
        __builtin_amdgcn_sched_barrier(0);
        __builtin_amdgcn_s_barrier();
        __builtin_amdgcn_sched_barrier(0);

        // ph2: stage B(t+2); read a1(t); MFMA q2; drain t+1
        if (pf) stageB(b, ktp);
        #pragma unroll
        for (int mf = 0; mf < 2; mf++)
            #pragma unroll
            for (int s = 0; s < 2; s++)
                a1[mf][s] = ld_frag(Asb, wm + 32 + mf * 16 + r15, s, quad, r7);
        __builtin_amdgcn_sched_barrier(0);
        __builtin_amdgcn_s_setprio(1);
        mfma8(0, 2, a0, b1);
        __builtin_amdgcn_s_setprio(0);
        __builtin_amdgcn_sched_barrier(0);
        if (pf) asm volatile("s_waitcnt vmcnt(4)" ::: "memory");
        else    asm volatile("s_waitcnt vmcnt(0)" ::: "memory");
        __builtin_amdgcn_s_barrier();
        __builtin_amdgcn_sched_barrier(0);

        // ph3: read a0(t+1); stage A(t+2); MFMA q3
        if (rd)
            #pragma unroll
            for (int mf = 0; mf < 2; mf++)
                #pragma unroll
                for (int s = 0; s < 2; s++)
                    a0[mf][s] = ld_frag(Aso, wm + mf * 16 + r15, s, quad, r7);
        if (pf) stageA(b, ktp);
        __builtin_amdgcn_sched_barrier(0);
        __builtin_amdgcn_s_setprio(1);
        mfma8(2, 2, a1, b1);
        __builtin_amdgcn_s_setprio(0);
        __builtin_amdgcn_sched_barrier(0);
        __builtin_amdgcn_s_barrier();
        __builtin_amdgcn_sched_barrier(0);

        // ph4: MFMA q4 (old b0); read b0(t+1)
        __builtin_amdgcn_s_setprio(1);
        mfma8(2, 0, a1, b0);
        __builtin_amdgcn_s_setprio(0);
        __builtin_amdgcn_sched_barrier(0);
        if (rd)
            #pragma unroll
            for (int nf = 0; nf < 2; nf++)
                #pragma unroll
                for (int s = 0; s < 2; s++)
                    b0[nf][s] = ld_frag(Bso, wn + nf * 16 + r15, s, quad, r7);
        __builtin_amdgcn_sched_barrier(0);
        __builtin_amdgcn_s_barrier();
        __builtin_amdgcn_sched_barrier(0);
    }

    // epilogue: fp32 direct stores (each output element written exactly once)
    #pragma unroll
    for (int mf = 0; mf < 4; mf++) {
        #pragma unroll
        for (int r = 0; r < 4; r++) {
            const size_t row = (size_t)(bm + wm + mf * 16 + quad * 4 + r);
            #pragma unroll
            for (int nf = 0; nf < 4; nf++) {
                const size_t col = (size_t)(bn + wn + nf * 16 + r15);
                C[row * D_MODEL + col] = acc[mf][nf][r];
            }
        }
    }
}

// ---------------------------------------------------------------------------
// Preproc q/k: conv(K=4)+SiLU+RMSNorm+RoPE, pure-register.
// q pre-scaled by 1/sqrt(HD); outer rotary negation dropped (cancels in qk^T).
// ---------------------------------------------------------------------------
__global__ __launch_bounds__(256) void preproc_qk_kernel(
    const __bf16* __restrict__ q_raw, const __bf16* __restrict__ k_raw,
    const float* __restrict__ cwq, const float* __restrict__ cwk,
    const float* __restrict__ qnw, const float* __restrict__ knw,
    const float* __restrict__ cosb, const float* __restrict__ sinb,
    __bf16* __restrict__ q_proc, __bf16* __restrict__ k_proc)
{
    const int t = blockIdx.x;
    const int which = blockIdx.y;
    const __bf16* X = which ? k_raw : q_raw;
    const float*  W = which ? cwk : cwq;
    const float*  nw = which ? knw : qnw;
    __bf16* P = which ? k_proc : q_proc;
    const float SC = which ? 1.0f : 0.08838834764831845f;  // 1/sqrt(128) folded into q

    const int tid = threadIdx.x;
    const int c0  = tid * 8;
    const int h   = tid >> 4;
    const int dl0 = (tid & 15) * 8;

    f32x4 wv[8];
    #pragma unroll
    for (int i = 0; i < 8; i++) wv[i] = *(const f32x4*)&W[(c0 + i) * 4];

    float acc[8] = {};
    #pragma unroll
    for (int j = 0; j < 4; j++) {
        int tt = t + j - 3;
        if (tt >= 0) {
            bf16x8 xv = *(const bf16x8*)&X[(size_t)tt * D_MODEL + c0];
            #pragma unroll
            for (int i = 0; i < 8; i++) acc[i] += (float)xv[i] * wv[i][j];
        }
    }
    float sil[8], ss = 0.f;
    #pragma unroll
    for (int i = 0; i < 8; i++) {
        float s = acc[i] / (1.f + __expf(-acc[i]));
        sil[i] = s; ss += s * s;
    }
    #pragma unroll
    for (int off = 1; off < 16; off <<= 1) ss += __shfl_xor(ss, off);
    float inv = rsqrtf(ss * (1.f / 128.f) + 1e-5f);

    f32x4 nv0 = *(const f32x4*)&nw[dl0];
    f32x4 nv1 = *(const f32x4*)&nw[dl0 + 4];
    float yn[8];
    #pragma unroll
    for (int i = 0; i < 8; i++) yn[i] = sil[i] * inv * (i < 4 ? nv0[i] : nv1[i - 4]);

    float partner[8];
    #pragma unroll
    for (int i = 0; i < 8; i++) partner[i] = __shfl_xor(yn[i], 4);  // dl ^ 32

    bf16x8 o;
    if (dl0 < RD_ROT) {
        f32x4 cv0 = *(const f32x4*)&cosb[t * RD_ROT + dl0];
        f32x4 cv1 = *(const f32x4*)&cosb[t * RD_ROT + dl0 + 4];
        f32x4 sv0 = *(const f32x4*)&sinb[t * RD_ROT + dl0];
        f32x4 sv1 = *(const f32x4*)&sinb[t * RD_ROT + dl0 + 4];
        #pragma unroll
        for (int i = 0; i < 8; i++) {
            int dl = dl0 + i;
            float c = i < 4 ? cv0[i] : cv1[i - 4];
            float s = i < 4 ? sv0[i] : sv1[i - 4];
            float rot = (dl < 32) ? -partner[i] : partner[i];  // rotate_half
            o[i] = (__bf16)((yn[i] * c + rot * s) * SC);
        }
    } else {
        #pragma unroll
        for (int i = 0; i < 8; i++) o[i] = (__bf16)(yn[i] * SC);
    }
    *(bf16x8*)&P[((size_t)h * T_SEQ + t) * HDIM + dl0] = o;
}

// ---------------------------------------------------------------------------
// Preproc v: conv+SiLU, transposed (H, HD, T) store, bf16x8 per thread.
// ---------------------------------------------------------------------------
__global__ __launch_bounds__(128) void preproc_v_kernel(
    const __bf16* __restrict__ v_raw, const float* __restrict__ cwv,
    __bf16* __restrict__ v_t)
{
    const int t0 = blockIdx.x * 8;
    const int h = blockIdx.y;
    const int dl = threadIdx.x;
    const int d = h * HDIM + dl;

    f32x4 wv = *(const f32x4*)&cwv[d * 4];
    float x[11];
    #pragma unroll
    for (int m = 0; m < 11; m++) {
        int tt = t0 - 3 + m;
        x[m] = (tt >= 0) ? (float)v_raw[(size_t)tt * D_MODEL + d] : 0.f;
    }
    bf16x8 o;
    #pragma unroll
    for (int r = 0; r < 8; r++) {
        float y = x[r] * wv[0] + x[r + 1] * wv[1] + x[r + 2] * wv[2] + x[r + 3] * wv[3];
        o[r] = (__bf16)(y / (1.f + __expf(-y)));
    }
    *(bf16x8*)&v_t[((size_t)h * HDIM + dl) * T_SEQ + t0] = o;
}

// ---------------------------------------------------------------------------
// Flash attention, causal — 4 waves x 16 q-rows, STATIC-MAX softmax,
// raw s_barrier + counted vmcnt, 2-deep staging (R4, verified).
// ---------------------------------------------------------------------------
__global__ __launch_bounds__(256, 2) void attn_kernel(
    const __bf16* __restrict__ Qp,   // (H, T, HD), pre-scaled
    const __bf16* __restrict__ Kp,   // (H, T, HD)
    const __bf16* __restrict__ Vt,   // (H, HD, T)
    __bf16* __restrict__ Op)         // (T, D)
{
    constexpr int TK = 64, PSTR = 72;
    __shared__ __align__(16) __bf16 Ks[2][TK * HDIM];   // 2 x 16 KB
    __shared__ __align__(16) __bf16 Vs[2][HDIM * TK];   // 2 x 16 KB
    __shared__ __align__(16) __bf16 Ps[64 * PSTR];      // 9 KB

    const int lane = threadIdx.x & 63;
    const int wave = threadIdx.x >> 6;
    const int r15  = lane & 15;
    const int quad = lane >> 4;
    const int h = blockIdx.y;
    const int qi = (blockIdx.y & 8) ? ((int)gridDim.x - 1 - (int)blockIdx.x) : (int)blockIdx.x;
    const int q0 = qi * TK;

    const __bf16* Kb = Kp + (size_t)h * T_SEQ * HDIM;
    const __bf16* Vb = Vt + (size_t)h * HDIM * T_SEQ;

    const int kchunk = wave * 4;
    const int krow_l = (lane >> 4);
    const int kg     = lane & 15;
    const int vrow_l = (lane >> 3);
    const int vg     = lane & 7;

    auto stage_tile = [&](int tile, int sb) {
        const int tkn = tile * TK;
        #pragma unroll
        for (int i = 0; i < 4; i++) {
            int ck = kchunk + i;
            int krow = ck * 4 + krow_l;
            int vrow = ck * 8 + vrow_l;
            async_copy16(Kb + (size_t)(tkn + krow) * HDIM + (kg ^ (krow & 15)) * 8, &Ks[sb][ck * 512]);
            async_copy16(Vb + (size_t)vrow * T_SEQ + tkn + (vg ^ (vrow & 7)) * 8, &Vs[sb][ck * 512]);
        }
    };

    bf16x8 qf[4];
    const __bf16* qbase = Qp + ((size_t)h * T_SEQ + q0 + wave * 16 + r15) * HDIM;
    #pragma unroll
    for (int s = 0; s < 4; s++) qf[s] = *(const bf16x8*)(qbase + s * 32 + quad * 8);

    f32x4 oacc[8] = {};
    float lsum[4] = {};

    const int ntk = qi + 1;

    // ---- prologue: 2-deep staging ----
    stage_tile(0, 0);
    if (ntk > 1) stage_tile(1, 1);

    for (int it = 0; it < ntk; it++) {
        const int buf = it & 1;
        const bool last = (it == ntk - 1);

        if (last) asm volatile("s_waitcnt vmcnt(0)" ::: "memory");   // only stage(it) left
        else      asm volatile("s_waitcnt vmcnt(8)" ::: "memory");   // drain it, keep it+1 flying
        __builtin_amdgcn_s_barrier();

        // ---- S = Q K^T ----
        f32x4 sacc[4] = {};
        #pragma unroll
        for (int s = 0; s < 4; s++) {
            #pragma unroll
            for (int nt = 0; nt < 4; nt++) {
                bf16x8 kf = *(const bf16x8*)&Ks[buf][(nt * 16 + r15) * HDIM + (((s * 4 + quad) ^ r15) << 3)];
                sacc[nt] = __builtin_amdgcn_mfma_f32_16x16x32_bf16(qf[s], kf, sacc[nt], 0, 0, 0);
            }
        }

        // ---- p = exp(s), static max; mask only on the diagonal tile ----
        #pragma unroll
        for (int nt = 0; nt < 4; nt++) {
            #pragma unroll
            for (int r = 0; r < 4; r++) {
                float p = __expf(sacc[nt][r]);
                if (last) {
                    int qrow = q0 + wave * 16 + quad * 4 + r;
                    int kcol = it * TK + nt * 16 + r15;
                    if (kcol > qrow) p = 0.f;
                }
                sacc[nt][r] = p;
                lsum[r] += p;
            }
        }

        // ---- P: C-layout -> LDS (wave-private rows, no barrier) ----
        #pragma unroll
        for (int nt = 0; nt < 4; nt++)
            #pragma unroll
            for (int r = 0; r < 4; r++)
                Ps[(wave * 16 + quad * 4 + r) * PSTR + nt * 16 + r15] = (__bf16)sacc[nt][r];

        // ---- O += P V ----
        #pragma unroll
        for (int s2 = 0; s2 < 2; s2++) {
            bf16x8 pf = *(const bf16x8*)&Ps[(wave * 16 + r15) * PSTR + s2 * 32 + quad * 8];
            #pragma unroll
            for (int nt = 0; nt < 8; nt++) {
                bf16x8 vf = *(const bf16x8*)&Vs[buf][(nt * 16 + r15) * TK + (((s2 * 4 + quad) ^ (r15 & 7)) << 3)];
                oacc[nt] = __builtin_amdgcn_mfma_f32_16x16x32_bf16(pf, vf, oacc[nt], 0, 0, 0);
            }
        }

        // ---- post-compute barrier, then stage it+2 into this buf ----
        __builtin_amdgcn_s_barrier();
        if (it + 2 < ntk) stage_tile(it + 2, buf);
    }

    #pragma unroll
    for (int r = 0; r < 4; r++) {
        float l = lsum[r];
        #pragma unroll
        for (int off = 1; off < 16; off <<= 1) l += __shfl_xor(l, off);
        float inv = 1.0f / l;
        size_t row = q0 + wave * 16 + quad * 4 + r;
        #pragma unroll
        for (int nt = 0; nt < 8; nt++)
            Op[row * D_MODEL + h * HDIM + nt * 16 + r15] = (__bf16)(oacc[nt][r] * inv);
    }
}

// ---------------------------------------------------------------------------
extern "C" void kernel_launch(void* const* d_in, const int* in_sizes, int n_in,
                              void* d_out, int out_size, void* d_ws, size_t ws_size,
                              hipStream_t stream) {
    (void)in_sizes; (void)n_in; (void)out_size; (void)ws_size;
    const float* hidden = (const float*)d_in[0];
    const float* cosb   = (const float*)d_in[1];
    const float* sinb   = (const float*)d_in[2];
    const float* Wq     = (const float*)d_in[3];
    const float* Wk     = (const float*)d_in[4];
    const float* Wv     = (const float*)d_in[5];
    const float* Wo     = (const float*)d_in[6];
    const float* cwq    = (const float*)d_in[7];
    const float* cwk    = (const float*)d_in[8];
    const float* cwv    = (const float*)d_in[9];
    const float* qnw    = (const float*)d_in[10];
    const float* knw    = (const float*)d_in[11];

    const size_t NEL = (size_t)T_SEQ * D_MODEL;
    __bf16* ws = (__bf16*)d_ws;
    __bf16* h_bf   = ws + 0 * NEL;   // later reused as attn_b
    __bf16* Wq_bf  = ws + 1 * NEL;   // Wq;Wk;Wv contiguous = fused B (6144x2048)
    __bf16* Wk_bf  = ws + 2 * NEL;
    __bf16* Wv_bf  = ws + 3 * NEL;
    __bf16* Wo_bf  = ws + 4 * NEL;   // persists to final GEMM
    __bf16* q_raw  = ws + 5 * NEL;   // q;k;v contiguous = fused C
    __bf16* k_raw  = ws + 6 * NEL;
    __bf16* v_raw  = ws + 7 * NEL;
    __bf16* q_proc = Wq_bf;          // reuse after GEMM
    __bf16* k_proc = Wk_bf;
    __bf16* v_t    = Wv_bf;
    __bf16* attn_b = h_bf;
    float*  out    = (float*)d_out;

    // 0. cast fp32 inputs to bf16
    cast_kernel<<<dim3(T_SEQ, 5), 256, 0, stream>>>(hidden, Wq, Wk, Wv, Wo,
                                                    h_bf, Wq_bf, Wk_bf, Wv_bf, Wo_bf);
    // 1. fused QKV GEMM — 256x192 tiles, 8x32 = 256 blocks, 32x32x16 MFMA
    gemm_qkv_fused_kernel<<<dim3(8, 32), 512, 0, stream>>>(h_bf, Wq_bf, q_raw);
    // 2. preproc
    preproc_qk_kernel<<<dim3(T_SEQ, 2), 256, 0, stream>>>(
        q_raw, k_raw, cwq, cwk, qnw, knw, cosb, sinb, q_proc, k_proc);
    preproc_v_kernel<<<dim3(T_SEQ / 8, NH), 128, 0, stream>>>(v_raw, cwv, v_t);
    // 3. causal flash attention — raw barriers + counted vmcnt, 2-deep staging
    attn_kernel<<<dim3(T_SEQ / 64, NH), 256, 0, stream>>>(q_proc, k_proc, v_t, attn_b);
    // 4. out = attn @ Wo^T — 128x128 pipelined, 256 blocks, fp32 direct stores
    proj_gemm_kernel<<<dim3(16, 16), 256, 0, stream>>>(attn_b, Wo_bf, out);
}